// Round 4
// baseline (616.831 us; speedup 1.0000x reference)
//
#include <hip/hip_runtime.h>

// LinearAttention: b=16, n=4096, dim=512, H=8, D=64, inner=512. T=65536 tokens.
// I/O dtype: fp32 (per reference). Compute: bf16 MFMA, fp32 accumulate.
// ws layout (77.3 MiB total):
//   wq_bf  [1536x512 bf16]  converted W_qkv
//   wo_bf  [ 512x512 bf16]  converted W_out
//   wsq    [65536x512 bf16] q' = act(x@Wq^T); overwritten in-place with attn
//   kvpart [512 x 5120 f32] per-(bh,s) kv partials (col e=64 = ksum)
//   kvt    [128 x 80x64 bf16] reduced kv, transposed [e][d]; row 64 = ksum

typedef unsigned short u16;
typedef u16 u16x4 __attribute__((ext_vector_type(4)));
typedef u16 u16x8 __attribute__((ext_vector_type(8)));
typedef __bf16 bf16x8 __attribute__((ext_vector_type(8)));
typedef float f32x4 __attribute__((ext_vector_type(4)));

__device__ __forceinline__ float bf2f(u16 x) {
    union { unsigned u; float f; } t; t.u = ((unsigned)x) << 16; return t.f;
}
__device__ __forceinline__ u16 f2bf(float f) {
    union { float f; unsigned u; } t; t.f = f;
    unsigned r = t.u + 0x7fffu + ((t.u >> 16) & 1u);   // RNE
    return (u16)(r >> 16);
}
__device__ __forceinline__ float act_fn(float v) {     // 1 + elu
    return v > 0.0f ? v + 1.0f : __expf(v);
}

// ---------------------------------------------------------------------------
// convert W_qkv (786432 f32) and W_out (262144 f32) to bf16. 1024x256 thr x4 el.
// ---------------------------------------------------------------------------
__global__ __launch_bounds__(256) void convert_w(const float* __restrict__ Wqkv,
                                                 const float* __restrict__ Wout,
                                                 u16* __restrict__ wq_bf,
                                                 u16* __restrict__ wo_bf)
{
    const size_t j = ((size_t)blockIdx.x * 256 + threadIdx.x) * 4;
    const float* src; u16* dst; size_t off;
    if (j < 786432) { src = Wqkv; dst = wq_bf; off = j; }
    else            { src = Wout; dst = wo_bf; off = j - 786432; }
    f32x4 v = *(const f32x4*)&src[off];
    u16x4 o = { f2bf(v[0]), f2bf(v[1]), f2bf(v[2]), f2bf(v[3]) };
    *(u16x4*)&dst[off] = o;
}

// ---------------------------------------------------------------------------
// gemm_q: wsq[t][c] = act( sum_k x[t][k] * Wq[c][k] ), c in [0,512).
// A fp32 (converted in staging), B bf16 rows 0..511 of wq_bf, K=512.
// 128x128 tile, BK=32, 256 thr (2x2 wave quadrants) — verified m92 pattern.
// ---------------------------------------------------------------------------
__global__ __launch_bounds__(256) void gemm_q(const float* __restrict__ A,
                                              const u16* __restrict__ Bw,
                                              u16* __restrict__ C)
{
    __shared__ u16 As[128 * 32];
    __shared__ u16 Bs[128 * 32];
    const int tid  = threadIdx.x;
    const int wave = tid >> 6, lane = tid & 63;
    const size_t row0 = (size_t)blockIdx.x * 128;
    const int    col0 = blockIdx.y * 128;
    const int wr = (wave >> 1) * 64, wc = (wave & 1) * 64;
    const int frow = lane & 15, quad = lane >> 4;

    f32x4 acc[4][4] = {};

    const int j0 = tid, j1 = tid + 256;
    const int r0 = j0 >> 2, c0 = (j0 & 3) * 8;
    const int r1 = j1 >> 2, c1 = (j1 & 3) * 8;
    const float* gA0 = A + (row0 + r0) * 512 + c0;
    const float* gA1 = A + (row0 + r1) * 512 + c1;
    const u16* gB0 = Bw + (size_t)(col0 + r0) * 512 + c0;
    const u16* gB1 = Bw + (size_t)(col0 + r1) * 512 + c1;

    for (int k0 = 0; k0 < 512; k0 += 32) {
        f32x4 a0l = *(const f32x4*)(gA0 + k0);
        f32x4 a0h = *(const f32x4*)(gA0 + k0 + 4);
        f32x4 a1l = *(const f32x4*)(gA1 + k0);
        f32x4 a1h = *(const f32x4*)(gA1 + k0 + 4);
        u16x8 b0 = *(const u16x8*)(gB0 + k0);
        u16x8 b1 = *(const u16x8*)(gB1 + k0);
        u16x8 a0 = { f2bf(a0l[0]), f2bf(a0l[1]), f2bf(a0l[2]), f2bf(a0l[3]),
                     f2bf(a0h[0]), f2bf(a0h[1]), f2bf(a0h[2]), f2bf(a0h[3]) };
        u16x8 a1 = { f2bf(a1l[0]), f2bf(a1l[1]), f2bf(a1l[2]), f2bf(a1l[3]),
                     f2bf(a1h[0]), f2bf(a1h[1]), f2bf(a1h[2]), f2bf(a1h[3]) };
        __syncthreads();
        *(u16x8*)&As[j0 * 8] = a0;
        *(u16x8*)&As[j1 * 8] = a1;
        *(u16x8*)&Bs[j0 * 8] = b0;
        *(u16x8*)&Bs[j1 * 8] = b1;
        __syncthreads();

        bf16x8 af[4], bfr[4];
#pragma unroll
        for (int mi = 0; mi < 4; ++mi)
            af[mi] = *(const bf16x8*)&As[(wr + mi * 16 + frow) * 32 + quad * 8];
#pragma unroll
        for (int ni = 0; ni < 4; ++ni)
            bfr[ni] = *(const bf16x8*)&Bs[(wc + ni * 16 + frow) * 32 + quad * 8];
#pragma unroll
        for (int mi = 0; mi < 4; ++mi)
#pragma unroll
            for (int ni = 0; ni < 4; ++ni)
                acc[mi][ni] = __builtin_amdgcn_mfma_f32_16x16x32_bf16(af[mi], bfr[ni], acc[mi][ni], 0, 0, 0);
    }

    // C/D layout: col = lane&15, row = quad*4 + reg  [measured m89/m91]
#pragma unroll
    for (int mi = 0; mi < 4; ++mi) {
#pragma unroll
        for (int ni = 0; ni < 4; ++ni) {
            const int c = col0 + wc + ni * 16 + frow;
            const size_t rbase = row0 + wr + mi * 16 + quad * 4;
#pragma unroll
            for (int reg = 0; reg < 4; ++reg)
                C[(rbase + reg) * 512 + c] = f2bf(act_fn(acc[mi][ni][reg]));
        }
    }
}

// ---------------------------------------------------------------------------
// kv_fused: per (bh, s): over 1024 tokens, [k|v]tile = x@Wkv_h^T by MFMA
// (act on k half), transpose via LDS, accumulate kv[d][e] by second MFMA.
// VT row 64 = ones => kvacc e=64 column = ksum. kvpart[(bh*4+s)][d*80+e].
// ---------------------------------------------------------------------------
__global__ __launch_bounds__(256) void kv_fused(const float* __restrict__ x,
                                                const u16* __restrict__ wbf,
                                                float* __restrict__ kvpart)
{
    __shared__ u16 As[128 * 32];
    __shared__ u16 KT[64 * 136];   // KT[d][n], pad 136
    __shared__ u16 VT[80 * 136];   // VT[e][n]; row 64 = ones, 65..79 = 0
    const int bh = blockIdx.x, s = blockIdx.y;
    const int b = bh >> 3, h = bh & 7;
    const int tid = threadIdx.x, wave = tid >> 6, lane = tid & 63;
    const int frow = lane & 15, quad = lane >> 4;
    const int wr = (wave >> 1) * 64, wc = (wave & 1) * 64;

    for (int i = tid; i < 16 * 136; i += 256)
        VT[64 * 136 + i] = (i < 136) ? (u16)0x3F80 : (u16)0;   // bf16 1.0 / 0

    const int j0 = tid, j1 = tid + 256;
    const int r0 = j0 >> 2, c0 = (j0 & 3) * 8;
    const int r1 = j1 >> 2, c1 = (j1 & 3) * 8;

    f32x4 kvacc[5] = {};   // d = wave*16 + quad*4 + reg ; e = ni*16 + frow

    for (int tile = 0; tile < 8; ++tile) {
        const size_t trow = (size_t)b * 4096 + s * 1024 + tile * 128;
        const float* gA0 = x + (trow + r0) * 512 + c0;
        const float* gA1 = x + (trow + r1) * 512 + c1;

        f32x4 cacc[4][4] = {};
        for (int k0 = 0; k0 < 512; k0 += 32) {
            f32x4 a0l = *(const f32x4*)(gA0 + k0);
            f32x4 a0h = *(const f32x4*)(gA0 + k0 + 4);
            f32x4 a1l = *(const f32x4*)(gA1 + k0);
            f32x4 a1h = *(const f32x4*)(gA1 + k0 + 4);
            u16x8 a0 = { f2bf(a0l[0]), f2bf(a0l[1]), f2bf(a0l[2]), f2bf(a0l[3]),
                         f2bf(a0h[0]), f2bf(a0h[1]), f2bf(a0h[2]), f2bf(a0h[3]) };
            u16x8 a1 = { f2bf(a1l[0]), f2bf(a1l[1]), f2bf(a1l[2]), f2bf(a1l[3]),
                         f2bf(a1h[0]), f2bf(a1h[1]), f2bf(a1h[2]), f2bf(a1h[3]) };
            __syncthreads();
            *(u16x8*)&As[j0 * 8] = a0;
            *(u16x8*)&As[j1 * 8] = a1;
            __syncthreads();

            bf16x8 af[4], bfr[4];
#pragma unroll
            for (int mi = 0; mi < 4; ++mi)
                af[mi] = *(const bf16x8*)&As[(wr + mi * 16 + frow) * 32 + quad * 8];
#pragma unroll
            for (int ni = 0; ni < 4; ++ni) {
                // local col wc+ni*16+frow: k-half -> W row 512+h*64+lc; v-half -> 1024+h*64+(lc-64)
                const size_t wrow = (size_t)((wc == 0 ? 512 : 1024) + h * 64 + ni * 16 + frow);
                bfr[ni] = *(const bf16x8*)&wbf[wrow * 512 + k0 + quad * 8];
            }
#pragma unroll
            for (int mi = 0; mi < 4; ++mi)
#pragma unroll
                for (int ni = 0; ni < 4; ++ni)
                    cacc[mi][ni] = __builtin_amdgcn_mfma_f32_16x16x32_bf16(af[mi], bfr[ni], cacc[mi][ni], 0, 0, 0);
        }

        // epilogue: C[n_local][col] -> KT[col][n] / VT[col-64][n]; act on k half
#pragma unroll
        for (int mi = 0; mi < 4; ++mi) {
#pragma unroll
            for (int ni = 0; ni < 4; ++ni) {
                const int lc = wc + ni * 16 + frow;
                const int n0 = wr + mi * 16 + quad * 4;
                u16x4 o;
#pragma unroll
                for (int reg = 0; reg < 4; ++reg) {
                    float v = cacc[mi][ni][reg];
                    if (wc == 0) v = act_fn(v);
                    o[reg] = f2bf(v);
                }
                if (wc == 0) *(u16x4*)&KT[lc * 136 + n0] = o;
                else         *(u16x4*)&VT[(lc - 64) * 136 + n0] = o;
            }
        }
        __syncthreads();

        // kv[d][e] += sum_n KT[d][n]*VT[e][n]  (K=128 over 4 chunks)
#pragma unroll
        for (int nc = 0; nc < 4; ++nc) {
            bf16x8 af2 = *(const bf16x8*)&KT[(wave * 16 + frow) * 136 + nc * 32 + quad * 8];
#pragma unroll
            for (int ni = 0; ni < 5; ++ni) {
                bf16x8 bf2 = *(const bf16x8*)&VT[(ni * 16 + frow) * 136 + nc * 32 + quad * 8];
                kvacc[ni] = __builtin_amdgcn_mfma_f32_16x16x32_bf16(af2, bf2, kvacc[ni], 0, 0, 0);
            }
        }
    }

    float* dst = kvpart + (size_t)(bh * 4 + s) * 5120;
#pragma unroll
    for (int ni = 0; ni < 5; ++ni) {
        const int e = ni * 16 + frow;
#pragma unroll
        for (int reg = 0; reg < 4; ++reg) {
            const int d = wave * 16 + quad * 4 + reg;
            dst[d * 80 + e] = kvacc[ni][reg];
        }
    }
}

// kvt[bh][e][d] bf16: e<65 = sum of 4 partials (transposed), 65..79 zero.
__global__ __launch_bounds__(256) void reduce_kvt(const float* __restrict__ kvpart,
                                                  u16* __restrict__ kvt)
{
    const int bh = blockIdx.x, tid = threadIdx.x;
    for (int i = tid; i < 5120; i += 256) {
        const int e = i >> 6, d = i & 63;
        float sum = 0.0f;
        if (e < 65) {
#pragma unroll
            for (int s = 0; s < 4; ++s)
                sum += kvpart[(size_t)(bh * 4 + s) * 5120 + d * 80 + e];
        }
        kvt[(size_t)bh * 5120 + i] = (e < 65) ? f2bf(sum) : (u16)0;
    }
}

// ---------------------------------------------------------------------------
// apply_attn: attnT[e][tok] = sum_d kvt[e][d] * q'[tok][d] by MFMA; row e=64
// gives denominator (shfl-broadcast); attn = num*z overwrites q' IN PLACE
// (per head: reads of head h's cols complete before its writes; blocks/waves
// own disjoint tokens). No LDS.
// ---------------------------------------------------------------------------
__global__ __launch_bounds__(256) void apply_attn(u16* __restrict__ qio,
                                                  const u16* __restrict__ kvt)
{
    const int blk = blockIdx.x;               // 512 blocks x 128 tokens
    const size_t t0 = (size_t)blk * 128;
    const int bb = blk >> 5;                  // batch = 32 blocks
    const int tid = threadIdx.x, wave = tid >> 6, lane = tid & 63;
    const int frow = lane & 15, quad = lane >> 4;
    const int wt = wave * 32;                 // wave owns 32 tokens

    for (int h = 0; h < 8; ++h) {
        const u16* kvh = kvt + (size_t)(bb * 8 + h) * 5120;
        f32x4 acc[5][2] = {};                 // mi: e-tile(80), ni: tok-tile(32)
#pragma unroll
        for (int kc = 0; kc < 2; ++kc) {      // d = kc*32 + quad*8 + j
            bf16x8 bfr[2];
#pragma unroll
            for (int ni = 0; ni < 2; ++ni)
                bfr[ni] = *(const bf16x8*)&qio[(t0 + wt + ni * 16 + frow) * 512 + h * 64 + kc * 32 + quad * 8];
#pragma unroll
            for (int mi = 0; mi < 5; ++mi) {
                bf16x8 afr = *(const bf16x8*)&kvh[(mi * 16 + frow) * 64 + kc * 32 + quad * 8];
#pragma unroll
                for (int ni = 0; ni < 2; ++ni)
                    acc[mi][ni] = __builtin_amdgcn_mfma_f32_16x16x32_bf16(afr, bfr[ni], acc[mi][ni], 0, 0, 0);
            }
        }
#pragma unroll
        for (int ni = 0; ni < 2; ++ni) {
            // den(tok) sits in row e=64: lanes quad==0, reg 0, col=tok&15
            const float den = __shfl(acc[4][ni][0], frow, 64);
            const float z = 1.0f / fmaxf(den, 1e-4f);
            const size_t tok = t0 + wt + ni * 16 + frow;
#pragma unroll
            for (int mi = 0; mi < 4; ++mi) {
                u16x4 o;
#pragma unroll
                for (int reg = 0; reg < 4; ++reg) o[reg] = f2bf(acc[mi][ni][reg] * z);
                *(u16x4*)&qio[tok * 512 + h * 64 + mi * 16 + quad * 4] = o;
            }
        }
    }
}

// ---------------------------------------------------------------------------
// gemm_out: out[t][c] (fp32) = sum_i attn[t][i]*Wout[c][i] + bias[c].
// A bf16 (wsq), B bf16 (wo_bf), C fp32.
// ---------------------------------------------------------------------------
__global__ __launch_bounds__(256) void gemm_out(const u16* __restrict__ A,
                                                const u16* __restrict__ Bw,
                                                float* __restrict__ C,
                                                const float* __restrict__ bias)
{
    __shared__ u16 As[128 * 32];
    __shared__ u16 Bs[128 * 32];
    const int tid  = threadIdx.x;
    const int wave = tid >> 6, lane = tid & 63;
    const size_t row0 = (size_t)blockIdx.x * 128;
    const int    col0 = blockIdx.y * 128;
    const int wr = (wave >> 1) * 64, wc = (wave & 1) * 64;
    const int frow = lane & 15, quad = lane >> 4;

    f32x4 acc[4][4] = {};

    const int j0 = tid, j1 = tid + 256;
    const int r0 = j0 >> 2, c0 = (j0 & 3) * 8;
    const int r1 = j1 >> 2, c1 = (j1 & 3) * 8;
    const u16* gA0 = A + (row0 + r0) * 512 + c0;
    const u16* gA1 = A + (row0 + r1) * 512 + c1;
    const u16* gB0 = Bw + (size_t)(col0 + r0) * 512 + c0;
    const u16* gB1 = Bw + (size_t)(col0 + r1) * 512 + c1;

    for (int k0 = 0; k0 < 512; k0 += 32) {
        u16x8 a0 = *(const u16x8*)(gA0 + k0);
        u16x8 a1 = *(const u16x8*)(gA1 + k0);
        u16x8 b0 = *(const u16x8*)(gB0 + k0);
        u16x8 b1 = *(const u16x8*)(gB1 + k0);
        __syncthreads();
        *(u16x8*)&As[j0 * 8] = a0;
        *(u16x8*)&As[j1 * 8] = a1;
        *(u16x8*)&Bs[j0 * 8] = b0;
        *(u16x8*)&Bs[j1 * 8] = b1;
        __syncthreads();

        bf16x8 af[4], bfr[4];
#pragma unroll
        for (int mi = 0; mi < 4; ++mi)
            af[mi] = *(const bf16x8*)&As[(wr + mi * 16 + frow) * 32 + quad * 8];
#pragma unroll
        for (int ni = 0; ni < 4; ++ni)
            bfr[ni] = *(const bf16x8*)&Bs[(wc + ni * 16 + frow) * 32 + quad * 8];
#pragma unroll
        for (int mi = 0; mi < 4; ++mi)
#pragma unroll
            for (int ni = 0; ni < 4; ++ni)
                acc[mi][ni] = __builtin_amdgcn_mfma_f32_16x16x32_bf16(af[mi], bfr[ni], acc[mi][ni], 0, 0, 0);
    }

#pragma unroll
    for (int mi = 0; mi < 4; ++mi) {
#pragma unroll
        for (int ni = 0; ni < 4; ++ni) {
            const int c = col0 + wc + ni * 16 + frow;
            const float bv = bias[c];
            const size_t rbase = row0 + wr + mi * 16 + quad * 4;
#pragma unroll
            for (int reg = 0; reg < 4; ++reg)
                C[(rbase + reg) * 512 + c] = acc[mi][ni][reg] + bv;
        }
    }
}

extern "C" void kernel_launch(void* const* d_in, const int* in_sizes, int n_in,
                              void* d_out, int out_size, void* d_ws, size_t ws_size,
                              hipStream_t stream)
{
    const float* x    = (const float*)d_in[0];   // [65536, 512] fp32
    const float* Wqkv = (const float*)d_in[1];   // [1536, 512]  fp32
    const float* Wout = (const float*)d_in[2];   // [512, 512]   fp32
    const float* bout = (const float*)d_in[3];   // [512]        fp32
    float* out = (float*)d_out;                  // [65536, 512] fp32
    char* ws = (char*)d_ws;

    u16*   wq_bf  = (u16*)ws;                    //  1,572,864 B
    u16*   wo_bf  = (u16*)(ws + 1572864ull);     //    524,288 B
    u16*   wsq    = (u16*)(ws + 2097152ull);     // 67,108,864 B
    float* kvpart = (float*)(ws + 69206016ull);  // 10,485,760 B
    u16*   kvt    = (u16*)(ws + 79691776ull);    //  1,310,720 B -> end 81,002,496

    // 0) weights -> bf16
    convert_w<<<1024, 256, 0, stream>>>(Wqkv, Wout, wq_bf, wo_bf);
    // 1) q' = act(x @ Wq^T) -> wsq (bf16)
    gemm_q<<<dim3(512, 4), 256, 0, stream>>>(x, wq_bf, wsq);
    // 2) fused k/v + kv/ksum partials (4-way token split)
    kv_fused<<<dim3(128, 4), 256, 0, stream>>>(x, wq_bf, kvpart);
    // 3) reduce -> transposed bf16 kvt (row e=64 = ksum)
    reduce_kvt<<<128, 256, 0, stream>>>(kvpart, kvt);
    // 4) attention apply, in-place on wsq (q' -> attn)
    apply_attn<<<512, 256, 0, stream>>>(wsq, kvt);
    // 5) out = attn @ Wout^T + b_out -> d_out (fp32)
    gemm_out<<<dim3(512, 4), 256, 0, stream>>>(wsq, wo_bf, out, bout);
}